// Round 2
// baseline (504.613 us; speedup 1.0000x reference)
//
#include <hip/hip_runtime.h>
#include <stdint.h>

typedef short s16x8 __attribute__((ext_vector_type(8)));
typedef float f32x4 __attribute__((ext_vector_type(4)));

#define MFMA16(a, b, c) __builtin_amdgcn_mfma_f32_16x16x32_bf16((a), (b), (c), 0, 0, 0)

__device__ __forceinline__ ushort f2b(float f) {
  union { float f; uint32_t u; } x; x.f = f;
  uint32_t r = x.u + 0x7fffu + ((x.u >> 16) & 1u);
  return (ushort)(r >> 16);
}
__device__ __forceinline__ float b2f(ushort s) {
  union { uint32_t u; float f; } x; x.u = ((uint32_t)s) << 16;
  return x.f;
}
// truncating pack of two floats -> two bf16 in one v_perm (used only for K·E bias; err ~1e-4 on logits)
__device__ __forceinline__ uint32_t pack2t(float a, float b) {
  return __builtin_amdgcn_perm(__float_as_uint(b), __float_as_uint(a), 0x07060302u);
}

__global__ __launch_bounds__(256) void cast_f32_bf16(const float* __restrict__ src,
                                                     ushort* __restrict__ dst, int n) {
  int i = (blockIdx.x * 256 + threadIdx.x) * 4;
  if (i + 4 <= n) {
    float4 v = *(const float4*)(src + i);
    ushort4 o; o.x = f2b(v.x); o.y = f2b(v.y); o.z = f2b(v.z); o.w = f2b(v.w);
    *(ushort4*)(dst + i) = o;
  }
}

__device__ __forceinline__ void gload16(const void* g, void* l) {
  __builtin_amdgcn_global_load_lds((const __attribute__((address_space(1))) void*)g,
                                   (__attribute__((address_space(3))) void*)l, 16, 0, 0);
}

// ---------------- QKV GEMM (unchanged from round 1): C[8192,3072] = X @ W^T
__global__ __launch_bounds__(256) void qkv_gemm(
    const ushort* __restrict__ hb, const ushort* __restrict__ wb,
    const float* __restrict__ bq, const float* __restrict__ bk, const float* __restrict__ bv,
    ushort* __restrict__ qb, ushort* __restrict__ kb, ushort* __restrict__ vt) {
  __shared__ ushort As[128 * 32];
  __shared__ ushort Bs[128 * 32];
  const int tid = threadIdx.x;
  const int w = tid >> 6, lane = tid & 63, quad = lane >> 4, l16 = lane & 15;
  const int m0 = blockIdx.y * 128, n0 = blockIdx.x * 128;

  const int srow = w * 32 + (lane >> 2);
  const int scol = (lane & 3) * 8;
  const ushort* ga = hb + (size_t)(m0 + srow) * 1024 + scol;
  const ushort* gw = wb + (size_t)(n0 + srow) * 1024 + scol;
  ushort* lA0 = As + (w * 32) * 32;
  ushort* lA1 = As + (w * 32 + 16) * 32;
  ushort* lB0 = Bs + (w * 32) * 32;
  ushort* lB1 = Bs + (w * 32 + 16) * 32;

  f32x4 acc[4][4];
#pragma unroll
  for (int mt = 0; mt < 4; ++mt)
#pragma unroll
    for (int nt = 0; nt < 4; ++nt) acc[mt][nt] = (f32x4){0.f, 0.f, 0.f, 0.f};

  const int wm = (w >> 1) * 64, wn = (w & 1) * 64;

  for (int k0 = 0; k0 < 1024; k0 += 32) {
    gload16(ga + k0, lA0);
    gload16(ga + k0 + 16 * 1024, lA1);
    gload16(gw + k0, lB0);
    gload16(gw + k0 + 16 * 1024, lB1);
    __syncthreads();
    s16x8 af[4], bfr[4];
#pragma unroll
    for (int mt = 0; mt < 4; ++mt)
      af[mt] = *(const s16x8*)(As + (wm + 16 * mt + l16) * 32 + quad * 8);
#pragma unroll
    for (int nt = 0; nt < 4; ++nt)
      bfr[nt] = *(const s16x8*)(Bs + (wn + 16 * nt + l16) * 32 + quad * 8);
#pragma unroll
    for (int mt = 0; mt < 4; ++mt)
#pragma unroll
      for (int nt = 0; nt < 4; ++nt)
        acc[mt][nt] = MFMA16(af[mt], bfr[nt], acc[mt][nt]);
    __syncthreads();
  }

  const int mat = n0 >> 10;
  const float* bias = (mat == 0) ? bq : ((mat == 1) ? bk : bv);
  const int b = m0 >> 10;
#pragma unroll
  for (int mt = 0; mt < 4; ++mt) {
    int mbase = m0 + wm + 16 * mt + 4 * quad;
#pragma unroll
    for (int nt = 0; nt < 4; ++nt) {
      int n = n0 + wn + 16 * nt + l16;
      int o = n & 1023; int hh = o >> 6; int d = o & 63;
      float bsv = bias[o];
#pragma unroll
      for (int reg = 0; reg < 4; ++reg) {
        int l = (mbase + reg) & 1023;
        ushort bx = f2b(acc[mt][nt][reg] + bsv);
        if (mat == 0)      qb[(((size_t)(b * 16 + hh)) * 1024 + l) * 64 + d] = bx;
        else if (mat == 1) kb[(((size_t)(b * 16 + hh)) * 1024 + l) * 64 + d] = bx;
        else               vt[(((size_t)(b * 16 + hh)) * 64 + d) * 1024 + l] = bx;
      }
    }
  }
}

// ---------------- Flash attention v2
// LDS (ushort units), all tiles stride-64 with XOR swizzle cb^(row&7):
//   RA  @0     (6400): initial Q staging -> SE2c (K·E compacted) -> P matrix
//   KS  @6400  (4096): K tile [r][d]
//   ES  @10496 (8192): E band [j 0..127][d]; V^T [d][r] aliases rows 0..63 late
// total 18688 us = 37376 B -> 4 blocks/CU.
#define RA  0
#define KSR 6400
#define ESR 10496

__device__ __forceinline__ const s16x8* fragp(const ushort* base, int row, int cb) {
  return (const s16x8*)(base + row * 64 + ((cb ^ (row & 7)) * 8));
}

__global__ __launch_bounds__(256, 4) void attn_kernel(
    const ushort* __restrict__ qb, const ushort* __restrict__ kb,
    const ushort* __restrict__ vt, const ushort* __restrict__ eb,
    const float* __restrict__ mask, float* __restrict__ out) {
  __shared__ __align__(16) ushort sm[18688];
  const int tid = threadIdx.x;
  const int w = tid >> 6, lane = tid & 63, quad = lane >> 4, l16 = lane & 15;
  const int bh = blockIdx.y, b = bh >> 4, h = bh & 15;
  const int l0 = blockIdx.x * 64;

  const int srow = lane >> 3;                  // 0..7
  const int colb = ((lane & 7) ^ srow) * 8;    // swizzled 16B chunk (row&7 == srow for all staging rows)
  const int row0 = w * 8 + srow;

  // ---- stage Q into RA (swizzled), hoist A-fragments
  {
    const ushort* qp = qb + ((size_t)bh * 1024 + l0 + row0) * 64 + colb;
    gload16(qp,           sm + RA + w * 512);
    gload16(qp + 2048,    sm + RA + 2048 + w * 512);
  }
  __syncthreads();
  s16x8 aq0, aq1;
  {
    int r = w * 16 + l16;
    aq0 = *fragp(sm + RA, r, quad);
    aq1 = *fragp(sm + RA, r, quad + 4);
  }

  const ushort* kp = kb + ((size_t)bh * 1024 + row0) * 64 + colb;
  const ushort* vp = vt + ((size_t)bh * 64 + row0) * 1024 + colb;
  const float* maskp = mask + b * 1024 + l16;

  float m_run[4], l_run[4];
  f32x4 o_acc[4];
#pragma unroll
  for (int r = 0; r < 4; ++r) { m_run[r] = -1e30f; l_run[r] = 0.f; }
#pragma unroll
  for (int nt = 0; nt < 4; ++nt) o_acc[nt] = (f32x4){0.f, 0.f, 0.f, 0.f};

  const float LOG2E = 1.44269504088896f;
  const float SC = 0.125f * LOG2E;

  for (int it = 0; it < 16; ++it) {
    const int r0 = it * 64;
    __syncthreads();  // A: all prior LDS readers done
    // stage K (2) + E band (4), async
    gload16(kp + r0 * 64,        sm + KSR + w * 512);
    gload16(kp + r0 * 64 + 2048, sm + KSR + 2048 + w * 512);
    {
      const int t0 = l0 - r0 + 960;
#pragma unroll
      for (int c = 0; c < 4; ++c) {
        int t = t0 + row0 + c * 32; if (t > 2046) t = 2046;
        gload16(eb + (size_t)t * 64 + colb, sm + ESR + c * 2048 + w * 512);
      }
    }
    float mkv[4];
#pragma unroll
    for (int nt = 0; nt < 4; ++nt) mkv[nt] = maskp[r0 + 16 * nt] * LOG2E;
    __syncthreads();  // B: K,E landed

    // S = Q K^T
    f32x4 zv[4];
#pragma unroll
    for (int nt = 0; nt < 4; ++nt) {
      int r = 16 * nt + l16;
      s16x8 bk0 = *fragp(sm + KSR, r, quad);
      s16x8 bk1 = *fragp(sm + KSR, r, quad + 4);
      f32x4 z = (f32x4){0.f, 0.f, 0.f, 0.f};
      z = MFMA16(aq0, bk0, z);
      z = MFMA16(aq1, bk1, z);
      zv[nt] = z;
    }
    // hoist K A-fragments (own rows) for phase B
    s16x8 ak0, ak1;
    {
      int r = w * 16 + l16;
      ak0 = *fragp(sm + KSR, r, quad);
      ak1 = *fragp(sm + KSR, r, quad + 4);
    }

    // phase A: d1[i] = Q @ E^T for j-blocks [w, w+4] (band-valid only)
    f32x4 d1[5];
#pragma unroll
    for (int i = 0; i < 5; ++i) {
      int jr = 16 * (w + i) + l16;
      s16x8 be0 = *fragp(sm + ESR, jr, quad);
      s16x8 be1 = *fragp(sm + ESR, jr, quad + 4);
      f32x4 z = (f32x4){0.f, 0.f, 0.f, 0.f};
      z = MFMA16(aq0, be0, z);
      z = MFMA16(aq1, be1, z);
      d1[i] = z;
    }
    // bias1 (Q-side) via intra-wave bpermute: value for (l=w16+4q+reg, j=l-r+63)
    // lives at lane (quad, (4q+reg+15-l16)&15), block 3-nt+(4q+reg>l16), register reg.
#pragma unroll
    for (int r = 0; r < 4; ++r) {
      int idx = (quad * 16 + ((4 * quad + r + 15 - l16) & 15)) * 4;
      float bp[5];
#pragma unroll
      for (int i = 0; i < 5; ++i)
        bp[i] = __int_as_float(__builtin_amdgcn_ds_bpermute(idx, __float_as_int(d1[i][r])));
      bool cnd = (4 * quad + r) > l16;
#pragma unroll
      for (int nt = 0; nt < 4; ++nt)
        zv[nt][r] += cnd ? bp[4 - nt] : bp[3 - nt];
    }

    // phase B: K @ E^T for j-blocks [3-w, 7-w]; compacted store SE2c[nt=w][jrel=16i+l16][rcol=4q..]
#pragma unroll
    for (int i = 0; i < 5; ++i) {
      int jr = 16 * (3 - w + i) + l16;
      s16x8 be0 = *fragp(sm + ESR, jr, quad);
      s16x8 be1 = *fragp(sm + ESR, jr, quad + 4);
      f32x4 z = (f32x4){0.f, 0.f, 0.f, 0.f};
      z = MFMA16(ak0, be0, z);
      z = MFMA16(ak1, be1, z);
      uint2 pk; pk.x = pack2t(z[0], z[1]); pk.y = pack2t(z[2], z[3]);
      *(uint2*)(sm + RA + w * 1600 + (16 * i + l16) * 20 + 4 * quad) = pk;
    }
    __syncthreads();  // C: SE2c visible; KS & ES(E) dead

    // stage V^T into ES rows 0..63 (async; drained by sync D2)
    gload16(vp + r0,        sm + ESR + w * 512);
    gload16(vp + r0 + 2048 * 16, sm + ESR + 2048 + w * 512);

    // bias2 (K-side) reads + scale + mask -> logits (base-2)
    float mloc[4] = {-3e38f, -3e38f, -3e38f, -3e38f};
    const int bb = (w * 16 + 4 * quad + 15 - l16) * 20 + l16;  // jrel*20 + rcol at nt=0,reg=0
#pragma unroll
    for (int nt = 0; nt < 4; ++nt) {
#pragma unroll
      for (int reg = 0; reg < 4; ++reg) {
        float z2 = (zv[nt][reg] + b2f(sm[RA + bb + nt * 1600 + reg * 20])) * SC + mkv[nt];
        zv[nt][reg] = z2;
        mloc[reg] = fmaxf(mloc[reg], z2);
      }
    }
    __syncthreads();  // D1: all bias2 reads done -> RA free for P

    // online softmax
#pragma unroll
    for (int off = 1; off < 16; off <<= 1)
#pragma unroll
      for (int reg = 0; reg < 4; ++reg)
        mloc[reg] = fmaxf(mloc[reg], __shfl_xor(mloc[reg], off));
    float scale[4], rsum[4];
#pragma unroll
    for (int reg = 0; reg < 4; ++reg) {
      float mn = fmaxf(m_run[reg], mloc[reg]);
      scale[reg] = exp2f(m_run[reg] - mn);
      m_run[reg] = mn;
      rsum[reg] = 0.f;
    }
#pragma unroll
    for (int nt = 0; nt < 4; ++nt)
#pragma unroll
      for (int reg = 0; reg < 4; ++reg) {
        float p = exp2f(zv[nt][reg] - m_run[reg]);
        zv[nt][reg] = p;
        rsum[reg] += p;
      }
#pragma unroll
    for (int off = 1; off < 16; off <<= 1)
#pragma unroll
      for (int reg = 0; reg < 4; ++reg)
        rsum[reg] += __shfl_xor(rsum[reg], off);
#pragma unroll
    for (int reg = 0; reg < 4; ++reg) l_run[reg] = l_run[reg] * scale[reg] + rsum[reg];
#pragma unroll
    for (int nt = 0; nt < 4; ++nt)
#pragma unroll
      for (int reg = 0; reg < 4; ++reg) o_acc[nt][reg] *= scale[reg];

    // P scatter into RA [l][r] (swizzled), rows wave-private
#pragma unroll
    for (int nt = 0; nt < 4; ++nt) {
      int r = 16 * nt + l16;
      int rcb = r >> 3, rlo = r & 7;
#pragma unroll
      for (int reg = 0; reg < 4; ++reg) {
        int l = w * 16 + 4 * quad + reg;
        sm[RA + l * 64 + ((rcb ^ (l & 7)) * 8) + rlo] = f2b(zv[nt][reg]);
      }
    }
    __syncthreads();  // D2: P visible + V drained (barrier vmcnt drain)

    // O += P @ V
#pragma unroll
    for (int kk = 0; kk < 2; ++kk) {
      s16x8 ap = *fragp(sm + RA, w * 16 + l16, kk * 4 + quad);
#pragma unroll
      for (int nt = 0; nt < 4; ++nt) {
        s16x8 bvf = *fragp(sm + ESR, 16 * nt + l16, kk * 4 + quad);
        o_acc[nt] = MFMA16(ap, bvf, o_acc[nt]);
      }
    }
  }

  // epilogue: out[b, l, h*64+d] = O / l_run
#pragma unroll
  for (int nt = 0; nt < 4; ++nt)
#pragma unroll
    for (int reg = 0; reg < 4; ++reg) {
      int l = l0 + w * 16 + 4 * quad + reg;
      int d = 16 * nt + l16;
      out[((size_t)(b * 1024 + l)) * 1024 + h * 64 + d] = o_acc[nt][reg] / l_run[reg];
    }
}

// ---------------- host launch
extern "C" void kernel_launch(void* const* d_in, const int* in_sizes, int n_in,
                              void* d_out, int out_size, void* d_ws, size_t ws_size,
                              hipStream_t stream) {
  const float* hidden = (const float*)d_in[0];
  const float* mask   = (const float*)d_in[1];
  const float* Wq     = (const float*)d_in[2];
  const float* bq     = (const float*)d_in[3];
  const float* Wk     = (const float*)d_in[4];
  const float* bk     = (const float*)d_in[5];
  const float* Wv     = (const float*)d_in[6];
  const float* bv     = (const float*)d_in[7];
  const float* dist   = (const float*)d_in[8];
  float* out = (float*)d_out;

  ushort* ws = (ushort*)d_ws;
  ushort* qb = ws;
  ushort* kb = ws + 8388608;
  ushort* vt = ws + 16777216;
  ushort* hb = ws + 25165824;
  ushort* wb = ws + 33554432;
  ushort* eb = ws + 36700160;

  cast_f32_bf16<<<8192, 256, 0, stream>>>(hidden, hb, 8388608);
  cast_f32_bf16<<<1024, 256, 0, stream>>>(Wq, wb, 1048576);
  cast_f32_bf16<<<1024, 256, 0, stream>>>(Wk, wb + 1048576, 1048576);
  cast_f32_bf16<<<1024, 256, 0, stream>>>(Wv, wb + 2097152, 1048576);
  cast_f32_bf16<<<128, 256, 0, stream>>>(dist, eb, 131008);

  qkv_gemm<<<dim3(24, 64), 256, 0, stream>>>(hb, wb, bq, bk, bv, qb, kb, vt);
  attn_kernel<<<dim3(16, 128), 256, 0, stream>>>(qb, kb, vt, eb, mask, out);
}

// Round 3
// 387.215 us; speedup vs baseline: 1.3032x; 1.3032x over previous
//
#include <hip/hip_runtime.h>
#include <stdint.h>

typedef short s16x8 __attribute__((ext_vector_type(8)));
typedef float f32x4 __attribute__((ext_vector_type(4)));

#define MFMA16(a, b, c) __builtin_amdgcn_mfma_f32_16x16x32_bf16((a), (b), (c), 0, 0, 0)

__device__ __forceinline__ ushort f2b(float f) {
  union { float f; uint32_t u; } x; x.f = f;
  uint32_t r = x.u + 0x7fffu + ((x.u >> 16) & 1u);
  return (ushort)(r >> 16);
}
__device__ __forceinline__ float b2f(ushort s) {
  union { uint32_t u; float f; } x; x.u = ((uint32_t)s) << 16;
  return x.f;
}
__device__ __forceinline__ uint32_t pack2t(float a, float b) {
  return __builtin_amdgcn_perm(__float_as_uint(b), __float_as_uint(a), 0x07060302u);
}

__global__ __launch_bounds__(256) void cast_f32_bf16(const float* __restrict__ src,
                                                     ushort* __restrict__ dst, int n) {
  int i = (blockIdx.x * 256 + threadIdx.x) * 4;
  if (i + 4 <= n) {
    float4 v = *(const float4*)(src + i);
    ushort4 o; o.x = f2b(v.x); o.y = f2b(v.y); o.z = f2b(v.z); o.w = f2b(v.w);
    *(ushort4*)(dst + i) = o;
  }
}

__device__ __forceinline__ void gload16(const void* g, void* l) {
  __builtin_amdgcn_global_load_lds((const __attribute__((address_space(1))) void*)g,
                                   (__attribute__((address_space(3))) void*)l, 16, 0, 0);
}

// ---------------- QKV GEMM (unchanged): C[8192,3072] = X @ W^T
__global__ __launch_bounds__(256) void qkv_gemm(
    const ushort* __restrict__ hb, const ushort* __restrict__ wb,
    const float* __restrict__ bq, const float* __restrict__ bk, const float* __restrict__ bv,
    ushort* __restrict__ qb, ushort* __restrict__ kb, ushort* __restrict__ vt) {
  __shared__ ushort As[128 * 32];
  __shared__ ushort Bs[128 * 32];
  const int tid = threadIdx.x;
  const int w = tid >> 6, lane = tid & 63, quad = lane >> 4, l16 = lane & 15;
  const int m0 = blockIdx.y * 128, n0 = blockIdx.x * 128;

  const int srow = w * 32 + (lane >> 2);
  const int scol = (lane & 3) * 8;
  const ushort* ga = hb + (size_t)(m0 + srow) * 1024 + scol;
  const ushort* gw = wb + (size_t)(n0 + srow) * 1024 + scol;
  ushort* lA0 = As + (w * 32) * 32;
  ushort* lA1 = As + (w * 32 + 16) * 32;
  ushort* lB0 = Bs + (w * 32) * 32;
  ushort* lB1 = Bs + (w * 32 + 16) * 32;

  f32x4 acc[4][4];
#pragma unroll
  for (int mt = 0; mt < 4; ++mt)
#pragma unroll
    for (int nt = 0; nt < 4; ++nt) acc[mt][nt] = (f32x4){0.f, 0.f, 0.f, 0.f};

  const int wm = (w >> 1) * 64, wn = (w & 1) * 64;

  for (int k0 = 0; k0 < 1024; k0 += 32) {
    gload16(ga + k0, lA0);
    gload16(ga + k0 + 16 * 1024, lA1);
    gload16(gw + k0, lB0);
    gload16(gw + k0 + 16 * 1024, lB1);
    __syncthreads();
    s16x8 af[4], bfr[4];
#pragma unroll
    for (int mt = 0; mt < 4; ++mt)
      af[mt] = *(const s16x8*)(As + (wm + 16 * mt + l16) * 32 + quad * 8);
#pragma unroll
    for (int nt = 0; nt < 4; ++nt)
      bfr[nt] = *(const s16x8*)(Bs + (wn + 16 * nt + l16) * 32 + quad * 8);
#pragma unroll
    for (int mt = 0; mt < 4; ++mt)
#pragma unroll
      for (int nt = 0; nt < 4; ++nt)
        acc[mt][nt] = MFMA16(af[mt], bfr[nt], acc[mt][nt]);
    __syncthreads();
  }

  const int mat = n0 >> 10;
  const float* bias = (mat == 0) ? bq : ((mat == 1) ? bk : bv);
  const int b = m0 >> 10;
#pragma unroll
  for (int mt = 0; mt < 4; ++mt) {
    int mbase = m0 + wm + 16 * mt + 4 * quad;
#pragma unroll
    for (int nt = 0; nt < 4; ++nt) {
      int n = n0 + wn + 16 * nt + l16;
      int o = n & 1023; int hh = o >> 6; int d = o & 63;
      float bsv = bias[o];
#pragma unroll
      for (int reg = 0; reg < 4; ++reg) {
        int l = (mbase + reg) & 1023;
        ushort bx = f2b(acc[mt][nt][reg] + bsv);
        if (mat == 0)      qb[(((size_t)(b * 16 + hh)) * 1024 + l) * 64 + d] = bx;
        else if (mat == 1) kb[(((size_t)(b * 16 + hh)) * 1024 + l) * 64 + d] = bx;
        else               vt[(((size_t)(b * 16 + hh)) * 64 + d) * 1024 + l] = bx;
      }
    }
  }
}

// ---------------- Flash attention v3: pipelined, 3 barriers/iter, static softmax
// LDS (ushort units), stride-64 rows, XOR swizzle cb^(row&7):
//   K dbuf  @0      2x4096
//   V dbuf  @8192   2x4096
//   E ring  @16384  3 segs x 64 rows x 64 = 12288 (window slides -64/iter)
//   SE2c    @28672  6400  (K·E compacted band)
//   P       @35072  4096  (Q staging at start, then P matrix)
// total 39168 us = 78336 B -> 2 blocks/CU (intentional: latency hidden by prefetch).
#define KR  0
#define VR  8192
#define ER  16384
#define SER 28672
#define PR  35072

__device__ __forceinline__ const s16x8* fragp(const ushort* base, int row, int cb) {
  return (const s16x8*)(base + row * 64 + ((cb ^ (row & 7)) * 8));
}

__global__ __launch_bounds__(256, 2) void attn_kernel(
    const ushort* __restrict__ qb, const ushort* __restrict__ kb,
    const ushort* __restrict__ vt, const ushort* __restrict__ eb,
    const float* __restrict__ mask, float* __restrict__ out) {
  __shared__ __align__(16) ushort sm[39168];
  const int tid = threadIdx.x;
  const int w = tid >> 6, lane = tid & 63, quad = lane >> 4, l16 = lane & 15;
  const int bh = blockIdx.y, b = bh >> 4, h = bh & 15;
  const int l0 = blockIdx.x * 64;

  const int srow = lane >> 3;                  // 0..7
  const int colb = ((lane & 7) ^ srow) * 8;    // swizzled 16B chunk on the global side
  const int row0 = w * 8 + srow;

  const ushort* kp = kb + ((size_t)bh * 1024 + row0) * 64 + colb;
  const ushort* vp = vt + ((size_t)bh * 64 + row0) * 1024 + colb;
  const float* maskp = mask + b * 1024 + l16;

  const int p0 = blockIdx.x % 3;               // E-ring segment of window start, it=0

  // ---- initial stage: Q -> PR, K(0) -> Kbuf0, V(0) -> Vbuf0, E window (128 rows)
  {
    const ushort* qp = qb + ((size_t)bh * 1024 + l0 + row0) * 64 + colb;
    gload16(qp,         sm + PR + w * 512);
    gload16(qp + 2048,  sm + PR + 2048 + w * 512);
    gload16(kp,         sm + KR + w * 512);
    gload16(kp + 2048,  sm + KR + 2048 + w * 512);
    gload16(vp,         sm + VR + w * 512);
    gload16(vp + 32768, sm + VR + 2048 + w * 512);
    const int t0i = l0 + 960;
#pragma unroll
    for (int c2 = 0; c2 < 4; ++c2) {
      int jb = w * 8 + 32 * c2;                // chunk base in window coords
      int seg = p0 + (jb >> 6); if (seg >= 3) seg -= 3;
      int t = t0i + jb + srow; if (t > 2046) t = 2046;
      gload16(eb + (size_t)t * 64 + colb, sm + ER + seg * 4096 + (jb & 63) * 64);
    }
  }
  __syncthreads();  // init (serves as X for it=0): all loads landed

  // hoist Q A-fragments (PR region is reused for P only after barrier C of it=0)
  s16x8 aq0, aq1;
  {
    int r = w * 16 + l16;
    aq0 = *fragp(sm + PR, r, quad);
    aq1 = *fragp(sm + PR, r, quad + 4);
  }

  float rsum[4];
  f32x4 o_acc[4];
#pragma unroll
  for (int r = 0; r < 4; ++r) rsum[r] = 0.f;
#pragma unroll
  for (int nt = 0; nt < 4; ++nt) o_acc[nt] = (f32x4){0.f, 0.f, 0.f, 0.f};

  const float LOG2E = 1.44269504088896f;
  const float SC = 0.125f * LOG2E;

  int s0 = p0;  // ring segment holding window start, decremented mod 3 per iter

  for (int it = 0; it < 16; ++it) {
    const int p = it & 1;
    const int r0 = it * 64;
    if (it > 0) __syncthreads();  // X: buf[p]/E landed (vmcnt drain), prev readers done

    // ---- prefetch it+1 (lands by X(it+1); disjoint from all buffers read this iter)
    {
      const int rn = (r0 + 64) & 1023;
      gload16(kp + rn * 64,        sm + KR + 4096 * (1 - p) + w * 512);
      gload16(kp + rn * 64 + 2048, sm + KR + 4096 * (1 - p) + 2048 + w * 512);
      gload16(vp + rn,             sm + VR + 4096 * (1 - p) + w * 512);
      gload16(vp + rn + 32768,     sm + VR + 4096 * (1 - p) + 2048 + w * 512);
      int pnew = s0 + 2; if (pnew >= 3) pnew -= 3;
      const int tb = l0 + 960 - r0 - 64;
#pragma unroll
      for (int c2 = 0; c2 < 2; ++c2) {
        int o = w * 8 + 32 * c2;
        int t = tb + o + srow; t = t < 0 ? 0 : (t > 2046 ? 2046 : t);
        gload16(eb + (size_t)t * 64 + colb, sm + ER + pnew * 4096 + o * 64);
      }
    }
    float mkv[4];
#pragma unroll
    for (int nt = 0; nt < 4; ++nt) mkv[nt] = maskp[r0 + 16 * nt] * LOG2E;

    const ushort* Kb = sm + KR + 4096 * p;
    const int sA = s0; int sB = s0 + 1; if (sB >= 3) sB -= 3;

    // ---- S = Q K^T
    f32x4 zv[4];
#pragma unroll
    for (int nt = 0; nt < 4; ++nt) {
      int r = 16 * nt + l16;
      s16x8 bk0 = *fragp(Kb, r, quad);
      s16x8 bk1 = *fragp(Kb, r, quad + 4);
      f32x4 z = (f32x4){0.f, 0.f, 0.f, 0.f};
      z = MFMA16(aq0, bk0, z);
      z = MFMA16(aq1, bk1, z);
      zv[nt] = z;
    }
    s16x8 ak0, ak1;
    {
      int r = w * 16 + l16;
      ak0 = *fragp(Kb, r, quad);
      ak1 = *fragp(Kb, r, quad + 4);
    }

    // ---- phase A: Q @ E^T, j-blocks w..w+4 (ring-mapped rows)
    f32x4 d1[5];
#pragma unroll
    for (int i = 0; i < 5; ++i) {
      int blk = w + i;
      int seg = (blk & 4) ? sB : sA;
      int row = seg * 64 + (blk & 3) * 16 + l16;
      s16x8 be0 = *fragp(sm + ER, row, quad);
      s16x8 be1 = *fragp(sm + ER, row, quad + 4);
      f32x4 z = (f32x4){0.f, 0.f, 0.f, 0.f};
      z = MFMA16(aq0, be0, z);
      z = MFMA16(aq1, be1, z);
      d1[i] = z;
    }
    // bias1 (Q-side) via intra-wave bpermute (verified round 2)
#pragma unroll
    for (int r = 0; r < 4; ++r) {
      int idx = (quad * 16 + ((4 * quad + r + 15 - l16) & 15)) * 4;
      float bp[5];
#pragma unroll
      for (int i = 0; i < 5; ++i)
        bp[i] = __int_as_float(__builtin_amdgcn_ds_bpermute(idx, __float_as_int(d1[i][r])));
      bool cnd = (4 * quad + r) > l16;
#pragma unroll
      for (int nt = 0; nt < 4; ++nt)
        zv[nt][r] += cnd ? bp[4 - nt] : bp[3 - nt];
    }

    // ---- phase B: K @ E^T, j-blocks 3-w..7-w -> SE2c (dedicated region)
#pragma unroll
    for (int i = 0; i < 5; ++i) {
      int blk = 3 - w + i;
      int seg = (blk & 4) ? sB : sA;
      int row = seg * 64 + (blk & 3) * 16 + l16;
      s16x8 be0 = *fragp(sm + ER, row, quad);
      s16x8 be1 = *fragp(sm + ER, row, quad + 4);
      f32x4 z = (f32x4){0.f, 0.f, 0.f, 0.f};
      z = MFMA16(ak0, be0, z);
      z = MFMA16(ak1, be1, z);
      uint2 pk; pk.x = pack2t(z[0], z[1]); pk.y = pack2t(z[2], z[3]);
      *(uint2*)(sm + SER + w * 1600 + (16 * i + l16) * 20 + 4 * quad) = pk;
    }
    __syncthreads();  // C: SE2c visible (cross-wave reads next)

    // ---- bias2 + scale + mask -> p = exp2(z2); static softmax (no running max)
    const int bb = (w * 16 + 4 * quad + 15 - l16) * 20 + l16;
#pragma unroll
    for (int nt = 0; nt < 4; ++nt) {
#pragma unroll
      for (int reg = 0; reg < 4; ++reg) {
        float z2 = (zv[nt][reg] + b2f(sm[SER + bb + nt * 1600 + reg * 20])) * SC + mkv[nt];
        float pe = exp2f(z2);
        zv[nt][reg] = pe;
        rsum[reg] += pe;
      }
    }

    // ---- P scatter into PR [l][r] (swizzled; rows wave-private)
#pragma unroll
    for (int nt = 0; nt < 4; ++nt) {
      int r = 16 * nt + l16;
      int rcb = r >> 3, rlo = r & 7;
#pragma unroll
      for (int reg = 0; reg < 4; ++reg) {
        int l = w * 16 + 4 * quad + reg;
        sm[PR + l * 64 + ((rcb ^ (l & 7)) * 8) + rlo] = f2b(zv[nt][reg]);
      }
    }
    __syncthreads();  // D: P visible

    // ---- O += P @ V
    const ushort* Vb = sm + VR + 4096 * p;
#pragma unroll
    for (int kk = 0; kk < 2; ++kk) {
      s16x8 ap = *fragp(sm + PR, w * 16 + l16, kk * 4 + quad);
#pragma unroll
      for (int nt = 0; nt < 4; ++nt) {
        s16x8 bvf = *fragp(Vb, 16 * nt + l16, kk * 4 + quad);
        o_acc[nt] = MFMA16(ap, bvf, o_acc[nt]);
      }
    }

    s0 = (s0 == 0) ? 2 : s0 - 1;  // window slides down 64 rows
  }

  // ---- final denominator reduce (once, not per-iter) + store
#pragma unroll
  for (int off = 1; off < 16; off <<= 1)
#pragma unroll
    for (int reg = 0; reg < 4; ++reg)
      rsum[reg] += __shfl_xor(rsum[reg], off);

#pragma unroll
  for (int nt = 0; nt < 4; ++nt)
#pragma unroll
    for (int reg = 0; reg < 4; ++reg) {
      int l = l0 + w * 16 + 4 * quad + reg;
      int d = 16 * nt + l16;
      out[((size_t)(b * 1024 + l)) * 1024 + h * 64 + d] = o_acc[nt][reg] / rsum[reg];
    }
}

// ---------------- host launch
extern "C" void kernel_launch(void* const* d_in, const int* in_sizes, int n_in,
                              void* d_out, int out_size, void* d_ws, size_t ws_size,
                              hipStream_t stream) {
  const float* hidden = (const float*)d_in[0];
  const float* mask   = (const float*)d_in[1];
  const float* Wq     = (const float*)d_in[2];
  const float* bq     = (const float*)d_in[3];
  const float* Wk     = (const float*)d_in[4];
  const float* bk     = (const float*)d_in[5];
  const float* Wv     = (const float*)d_in[6];
  const float* bv     = (const float*)d_in[7];
  const float* dist   = (const float*)d_in[8];
  float* out = (float*)d_out;

  ushort* ws = (ushort*)d_ws;
  ushort* qb = ws;
  ushort* kb = ws + 8388608;
  ushort* vt = ws + 16777216;
  ushort* hb = ws + 25165824;
  ushort* wb = ws + 33554432;
  ushort* eb = ws + 36700160;

  cast_f32_bf16<<<8192, 256, 0, stream>>>(hidden, hb, 8388608);
  cast_f32_bf16<<<1024, 256, 0, stream>>>(Wq, wb, 1048576);
  cast_f32_bf16<<<1024, 256, 0, stream>>>(Wk, wb + 1048576, 1048576);
  cast_f32_bf16<<<1024, 256, 0, stream>>>(Wv, wb + 2097152, 1048576);
  cast_f32_bf16<<<128, 256, 0, stream>>>(dist, eb, 131008);

  qkv_gemm<<<dim3(24, 64), 256, 0, stream>>>(hb, wb, bq, bk, bv, qb, kb, vt);
  attn_kernel<<<dim3(16, 128), 256, 0, stream>>>(qb, kb, vt, eb, mask, out);
}